// Round 5
// baseline (13.697 us; speedup 1.0000x reference)
//
#include <hip/hip_runtime.h>

// Closed-form collapse of the 8-qubit circuit (per 8-wide head group, wire i = k&7):
//   i=0: q = cos(x[base+4]) * cos(x_k + p0)
//   i=1: q = cos(x_k)
//   i=2: q = cos(x[base+1]) * cos(x_k)
//   i=3: q = cos(p1) * cos(x_k)
//   i=4: q = cos(x_k)
//   i=5: q = cos(x_k)
//   i=6: q = cos(x_k + p3)
//   i=7: q = cos(p4) * cos(x_k)
// then out[row] = q[row] @ W^T + b   (64x64 GEMV per row)
//
// Round-4 analysis: exec is LDS-broadcast-bound (64 ds_read_b128/wave ~= 2.4us
// device-wide). This version halves DS reads: each lane owns 2 output columns
// (l5, l5+32; W held in 128 VGPRs), each half-wave owns one row of a pair, so
// one broadcast ds_read_b128 feeds 8 FMAs instead of 4.

#define BLOCK 256
#define WAVES 4
#define ROWS_PER_WAVE 4
#define ROWS_PER_BLOCK (WAVES * ROWS_PER_WAVE)   // 16 -> 512 blocks for 8192 rows

__global__ __launch_bounds__(BLOCK, 2) void qattn_kernel(
    const float* __restrict__ x,      // (rows, 64)
    const float* __restrict__ W,      // (64, 64) row-major: W[j][k]
    const float* __restrict__ bvec,   // (64,)
    const float* __restrict__ qp,     // (6,)
    float* __restrict__ out,          // (rows, 64)
    int nrows)
{
    __shared__ float qbuf[WAVES][2][2][64];      // [wave][pair][half][k]

    const int lane = threadIdx.x & 63;
    const int wv   = threadIdx.x >> 6;
    const int half = lane >> 5;                  // which row of the pair
    const int l5   = lane & 31;                  // column / k-index base

    const int row0 = (blockIdx.x * WAVES + wv) * ROWS_PER_WAVE;
    if (row0 >= nrows) return;                   // 8192 % 16 == 0: full groups

    const int rA = row0 + half;                  // pair-0 row for this half
    const int rB = row0 + 2 + half;              // pair-1 row

    // ---- issue x loads first: deepest dependency chain ----
    const float xa0 = x[rA * 64 + l5];
    const float xb0 = x[rA * 64 + l5 + 32];
    const float xa1 = x[rB * 64 + l5];
    const float xb1 = x[rB * 64 + l5 + 32];

    // ---- W: 2 output columns per lane, 32 float4 in registers ----
    float4 wregA[16], wregB[16];
    const float4* WA = reinterpret_cast<const float4*>(W + l5 * 64);
    const float4* WB = reinterpret_cast<const float4*>(W + (l5 + 32) * 64);
    #pragma unroll
    for (int kk = 0; kk < 16; ++kk) { wregA[kk] = WA[kk]; wregB[kk] = WB[kk]; }

    const float biasA = bvec[l5];
    const float biasB = bvec[l5 + 32];
    const float p0 = qp[0], p1 = qp[1], p3 = qp[3], p4 = qp[4];
    const float cp1 = __cosf(p1);
    const float cp4 = __cosf(p4);

    const int   i    = l5 & 7;                       // wire index (same for k and k+32)
    const float add  = (i == 0) ? p0 : (i == 6) ? p3 : 0.0f;
    const float cfac = (i == 3) ? cp1 : (i == 7) ? cp4 : 1.0f;
    const int   src4 = (lane & 56) | 4;              // same half, head-base+4
    const int   src1 = (lane & 56) | 1;              // same half, head-base+1

    // ---- pair 0 expectations ----
    const float ca0 = __cosf(xa0 + add), cb0 = __cosf(xb0 + add);
    const float s4a0 = __shfl(ca0, src4, 64), s4b0 = __shfl(cb0, src4, 64);
    const float s1a0 = __shfl(ca0, src1, 64), s1b0 = __shfl(cb0, src1, 64);
    const float fa0 = (i == 0) ? s4a0 : (i == 2) ? s1a0 : cfac;
    const float fb0 = (i == 0) ? s4b0 : (i == 2) ? s1b0 : cfac;
    qbuf[wv][0][half][l5]      = fa0 * ca0;
    qbuf[wv][0][half][l5 + 32] = fb0 * cb0;

    // ---- pair 1 expectations ----
    const float ca1 = __cosf(xa1 + add), cb1 = __cosf(xb1 + add);
    const float s4a1 = __shfl(ca1, src4, 64), s4b1 = __shfl(cb1, src4, 64);
    const float s1a1 = __shfl(ca1, src1, 64), s1b1 = __shfl(cb1, src1, 64);
    const float fa1 = (i == 0) ? s4a1 : (i == 2) ? s1a1 : cfac;
    const float fb1 = (i == 0) ? s4b1 : (i == 2) ? s1b1 : cfac;
    qbuf[wv][1][half][l5]      = fa1 * ca1;
    qbuf[wv][1][half][l5 + 32] = fb1 * cb1;

    // ---- GEMV: 32 broadcast ds_read_b128, 256 FMAs, 4 independent chains ----
    // (write->read is same-wave, in-order DS pipe + compiler lgkmcnt: no barrier)
    float accA0 = biasA, accB0 = biasB, accA1 = biasA, accB1 = biasB;
    const float4* q0 = reinterpret_cast<const float4*>(qbuf[wv][0][half]);
    const float4* q1 = reinterpret_cast<const float4*>(qbuf[wv][1][half]);
    #pragma unroll
    for (int kk = 0; kk < 16; ++kk) {
        const float4 a = q0[kk];
        const float4 b = q1[kk];
        accA0 = fmaf(a.x, wregA[kk].x, accA0);
        accA0 = fmaf(a.y, wregA[kk].y, accA0);
        accA0 = fmaf(a.z, wregA[kk].z, accA0);
        accA0 = fmaf(a.w, wregA[kk].w, accA0);
        accB0 = fmaf(a.x, wregB[kk].x, accB0);
        accB0 = fmaf(a.y, wregB[kk].y, accB0);
        accB0 = fmaf(a.z, wregB[kk].z, accB0);
        accB0 = fmaf(a.w, wregB[kk].w, accB0);
        accA1 = fmaf(b.x, wregA[kk].x, accA1);
        accA1 = fmaf(b.y, wregA[kk].y, accA1);
        accA1 = fmaf(b.z, wregA[kk].z, accA1);
        accA1 = fmaf(b.w, wregA[kk].w, accA1);
        accB1 = fmaf(b.x, wregB[kk].x, accB1);
        accB1 = fmaf(b.y, wregB[kk].y, accB1);
        accB1 = fmaf(b.z, wregB[kk].z, accB1);
        accB1 = fmaf(b.w, wregB[kk].w, accB1);
    }

    out[rA * 64 + l5]      = accA0;
    out[rA * 64 + l5 + 32] = accB0;
    out[rB * 64 + l5]      = accA1;
    out[rB * 64 + l5 + 32] = accB1;
}

extern "C" void kernel_launch(void* const* d_in, const int* in_sizes, int n_in,
                              void* d_out, int out_size, void* d_ws, size_t ws_size,
                              hipStream_t stream) {
    const float* x  = (const float*)d_in[0];   // (B,S,E) = (8,1024,64)
    const float* W  = (const float*)d_in[1];   // (64,64)
    const float* b  = (const float*)d_in[2];   // (64,)
    const float* qp = (const float*)d_in[3];   // (6,)
    float* out = (float*)d_out;                // (8,1024,64)

    const int nrows  = in_sizes[0] / 64;       // B*S = 8192
    const int blocks = (nrows + ROWS_PER_BLOCK - 1) / ROWS_PER_BLOCK;  // 512

    qattn_kernel<<<blocks, BLOCK, 0, stream>>>(x, W, b, qp, out, nrows);
}

// Round 6
// 10.898 us; speedup vs baseline: 1.2569x; 1.2569x over previous
//
#include <hip/hip_runtime.h>

// Closed-form collapse of the 8-qubit circuit (per 8-wide head group, wire i = lane&7):
//   i=0: q = cos(x[base+4]) * cos(x_i + p0)
//   i=1: q = cos(x_i)
//   i=2: q = cos(x[base+1]) * cos(x_i)
//   i=3: q = cos(p1) * cos(x_i)
//   i=4,5: q = cos(x_i)
//   i=6: q = cos(x_i + p3)
//   i=7: q = cos(p4) * cos(x_i)
// then out[row] = q[row] @ W^T + b   (64x64 GEMV per row)
//
// R6: same shape as the R1 winner (512 blocks, W row per lane, coalesced
// scalar x loads) but the LDS q-broadcast is replaced by v_readlane SGPR
// broadcast (q[k] is wave-uniform per row), and the 4 rows' FMA chains are
// interleaved kk-major so the 4-cycle FMA latency is hidden. Zero LDS.

#define BLOCK 256
#define WAVES 4
#define ROWS_PER_WAVE 4
#define ROWS_PER_BLOCK (WAVES * ROWS_PER_WAVE)   // 16 -> 512 blocks for 8192 rows

__device__ __forceinline__ float bcast_lane(float v, int srclane) {
    return __builtin_bit_cast(float,
        __builtin_amdgcn_readlane(__builtin_bit_cast(int, v), srclane));
}

__global__ __launch_bounds__(BLOCK) void qattn_kernel(
    const float* __restrict__ x,      // (rows, 64)
    const float* __restrict__ W,      // (64, 64) row-major: W[j][k]
    const float* __restrict__ bvec,   // (64,)
    const float* __restrict__ qp,     // (6,)
    float* __restrict__ out,          // (rows, 64)
    int nrows)
{
    const int lane = threadIdx.x & 63;
    const int wv   = threadIdx.x >> 6;

    const int row0 = (blockIdx.x * WAVES + wv) * ROWS_PER_WAVE;
    if (row0 >= nrows) return;                   // 8192 % 16 == 0

    // ---- issue x loads first (deepest chain), coalesced 256B per row ----
    float xv[ROWS_PER_WAVE];
    #pragma unroll
    for (int r = 0; r < ROWS_PER_WAVE; ++r)
        xv[r] = x[(row0 + r) * 64 + lane];

    // ---- W row of this lane's output column, scalarized to 64 regs ----
    float wr[64];
    const float4* W4 = reinterpret_cast<const float4*>(W + lane * 64);
    #pragma unroll
    for (int kk = 0; kk < 16; ++kk) {
        const float4 t = W4[kk];
        wr[4 * kk + 0] = t.x;
        wr[4 * kk + 1] = t.y;
        wr[4 * kk + 2] = t.z;
        wr[4 * kk + 3] = t.w;
    }

    const float bias = bvec[lane];
    const float p0 = qp[0], p1 = qp[1], p3 = qp[3], p4 = qp[4];
    const float cp1 = __cosf(p1);
    const float cp4 = __cosf(p4);

    const int   i    = lane & 7;     // wire index within head
    const int   base = lane & ~7;    // first lane of this head's group
    const float add  = (i == 0) ? p0 : (i == 6) ? p3 : 0.0f;
    const float cfac = (i == 3) ? cp1 : (i == 7) ? cp4 : 1.0f;

    // ---- quantum expectations, q[r] lives in lane = k ----
    float q[ROWS_PER_WAVE];
    #pragma unroll
    for (int r = 0; r < ROWS_PER_WAVE; ++r) {
        const float xo4 = __shfl(xv[r], base + 4, 64);
        const float xo1 = __shfl(xv[r], base + 1, 64);
        const float c4  = __cosf(xo4);
        const float c1  = __cosf(xo1);
        const float fac = (i == 0) ? c4 : (i == 2) ? c1 : cfac;
        q[r] = fac * __cosf(xv[r] + add);
    }

    // ---- GEMV via readlane broadcast: 4 independent FMA chains ----
    float acc[ROWS_PER_WAVE] = {bias, bias, bias, bias};
    #pragma unroll
    for (int kk = 0; kk < 64; ++kk) {
        const float w = wr[kk];
        #pragma unroll
        for (int r = 0; r < ROWS_PER_WAVE; ++r)
            acc[r] = fmaf(bcast_lane(q[r], kk), w, acc[r]);
    }

    #pragma unroll
    for (int r = 0; r < ROWS_PER_WAVE; ++r)
        out[(row0 + r) * 64 + lane] = acc[r];    // coalesced 256B stores
}

extern "C" void kernel_launch(void* const* d_in, const int* in_sizes, int n_in,
                              void* d_out, int out_size, void* d_ws, size_t ws_size,
                              hipStream_t stream) {
    const float* x  = (const float*)d_in[0];   // (B,S,E) = (8,1024,64)
    const float* W  = (const float*)d_in[1];   // (64,64)
    const float* b  = (const float*)d_in[2];   // (64,)
    const float* qp = (const float*)d_in[3];   // (6,)
    float* out = (float*)d_out;                // (8,1024,64)

    const int nrows  = in_sizes[0] / 64;       // B*S = 8192
    const int blocks = (nrows + ROWS_PER_BLOCK - 1) / ROWS_PER_BLOCK;  // 512

    qattn_kernel<<<blocks, BLOCK, 0, stream>>>(x, W, b, qp, out, nrows);
}